// Round 1
// baseline (90.689 us; speedup 1.0000x reference)
//
#include <hip/hip_runtime.h>
#include <hip/hip_bf16.h>

typedef short bf16x8 __attribute__((ext_vector_type(8)));
typedef float f32x4 __attribute__((ext_vector_type(4)));
typedef unsigned short u16;
typedef u16 u16x8 __attribute__((ext_vector_type(8)));
typedef u16 u16x4 __attribute__((ext_vector_type(4)));

constexpr int NB = 8, NT = 2048, NC = 1024, NH = 64;
constexpr float L2E = 1.4426950408889634f;

__device__ __forceinline__ u16 f2bf(float f) {
  __hip_bfloat16 h = __float2bfloat16(f);
  return __builtin_bit_cast(u16, h);
}
__device__ __forceinline__ bf16x8 ldsv8(const u16* p) {
  return __builtin_bit_cast(bf16x8, *(const u16x8*)p);
}

// ---------------- kernel 0: W fp32 [C][H] -> bf16 W^T [3][H][C], q scaled by 0.125
__global__ __launch_bounds__(256) void wconv(const float* __restrict__ wk,
                                             const float* __restrict__ wq,
                                             const float* __restrict__ wv,
                                             u16* __restrict__ wb) {
  int idx = blockIdx.x * 256 + threadIdx.x;   // 3*64*1024 = 196608 exact
  int m = idx >> 16;
  int rem = idx & 65535;
  int n = rem >> 10, kk = rem & 1023;
  const float* src = (m == 0) ? wq : ((m == 1) ? wk : wv);
  float f = src[kk * NH + n];
  if (m == 0) f *= 0.125f;                    // fold 1/sqrt(H) into Wq
  wb[idx] = f2bf(f);
}

// ---------------- kernel 1: fused QKV projection (x read once)
// out: qg,kg = [B*T][H] bf16 ; vtg = [B][H][T] bf16 (transposed for flash PV)
__global__ __launch_bounds__(256) void qkv_proj(const float* __restrict__ x,
                                                const u16* __restrict__ wb,
                                                u16* __restrict__ qg,
                                                u16* __restrict__ kg,
                                                u16* __restrict__ vtg) {
  __shared__ __align__(16) u16 xs[64 * 72];
  __shared__ __align__(16) u16 wt[3 * 64 * 72];
  const int tid = threadIdx.x;
  const int w = tid >> 6, l = tid & 63;
  const int lr = l & 15, lg = l >> 4;
  const int row0 = blockIdx.x * 64;

  f32x4 acc[3][4];
#pragma unroll
  for (int m = 0; m < 3; ++m)
#pragma unroll
    for (int nt = 0; nt < 4; ++nt) acc[m][nt] = (f32x4){0.f, 0.f, 0.f, 0.f};

  for (int kb = 0; kb < 16; ++kb) {
    const int kbase = kb * 64;
    // stage x tile [64 rows][64 k] -> bf16 LDS
#pragma unroll
    for (int i = 0; i < 4; ++i) {
      int flat = tid + 256 * i;            // 1024 float4s
      int r = flat >> 4, c4 = (flat & 15) * 4;
      float4 v = *(const float4*)(x + (row0 + r) * NC + kbase + c4);
      u16x4 pk = {f2bf(v.x), f2bf(v.y), f2bf(v.z), f2bf(v.w)};
      *(u16x4*)&xs[r * 72 + c4] = pk;
    }
    // stage W^T chunk [3][64 n][64 k]
#pragma unroll
    for (int i = 0; i < 6; ++i) {
      int flat = tid + 256 * i;            // 1536 vec8s
      int m = flat >> 9, rem = flat & 511;
      int n = rem >> 3, c8 = (rem & 7) * 8;
      u16x8 v = *(const u16x8*)(wb + m * 65536 + n * 1024 + kbase + c8);
      *(u16x8*)&wt[(m * 64 + n) * 72 + c8] = v;
    }
    __syncthreads();
    bf16x8 af[2];
#pragma unroll
    for (int ks = 0; ks < 2; ++ks)
      af[ks] = ldsv8(&xs[(w * 16 + lr) * 72 + ks * 32 + lg * 8]);
#pragma unroll
    for (int m = 0; m < 3; ++m)
#pragma unroll
      for (int nt = 0; nt < 4; ++nt)
#pragma unroll
        for (int ks = 0; ks < 2; ++ks) {
          bf16x8 bf = ldsv8(&wt[(m * 64 + nt * 16 + lr) * 72 + ks * 32 + lg * 8]);
          acc[m][nt] = __builtin_amdgcn_mfma_f32_16x16x32_bf16(af[ks], bf, acc[m][nt], 0, 0, 0);
        }
    __syncthreads();
  }

  // epilogue: q,k direct bf16 stores (D layout: row = 4*lg+r, col = 16*nt+lr)
#pragma unroll
  for (int nt = 0; nt < 4; ++nt)
#pragma unroll
    for (int r = 0; r < 4; ++r) {
      int grow = row0 + w * 16 + lg * 4 + r;
      int col = nt * 16 + lr;
      qg[grow * NH + col] = f2bf(acc[0][nt][r]);
      kg[grow * NH + col] = f2bf(acc[1][nt][r]);
    }
  // v: transpose through LDS (reuse xs), store [B][H][T]
#pragma unroll
  for (int nt = 0; nt < 4; ++nt)
#pragma unroll
    for (int r = 0; r < 4; ++r)
      xs[(w * 16 + lg * 4 + r) * 72 + nt * 16 + lr] = f2bf(acc[2][nt][r]);
  __syncthreads();
  int b = row0 >> 11;
  int t0 = row0 & 2047;
#pragma unroll
  for (int i = 0; i < 2; ++i) {
    int flat = tid + 256 * i;              // 512 vec8s: 64 h-rows x 8
    int h = flat >> 3, tc = (flat & 7) * 8;
    u16x8 v;
#pragma unroll
    for (int j = 0; j < 8; ++j) v[j] = xs[(tc + j) * 72 + h];
    *(u16x8*)(vtg + (b * NH + h) * NT + t0 + tc) = v;
  }
}

// ---------------- kernel 2: causal flash attention
// grid = B*32 blocks (qt tiles of 64 rows), 4 waves x 16 q-rows
__global__ __launch_bounds__(256) void flash(const u16* __restrict__ qg,
                                             const u16* __restrict__ kg,
                                             const u16* __restrict__ vtg,
                                             float* __restrict__ out) {
  __shared__ __align__(16) u16 ksl[64 * 72];
  __shared__ __align__(16) u16 vsl[64 * 72];   // V^T: rows=h, cols=kv
  __shared__ __align__(16) u16 pl[4 * 16 * 72];
  const int tid = threadIdx.x;
  const int w = tid >> 6, l = tid & 63;
  const int lr = l & 15, lg = l >> 4;
  const int b = blockIdx.x >> 5, qt = blockIdx.x & 31;

  // Q A-frags: A[m=lr][k=h], already scaled by 0.125 via Wq
  bf16x8 qf[2];
  const int qrow = b * NT + qt * 64 + w * 16 + lr;
#pragma unroll
  for (int ks = 0; ks < 2; ++ks)
    qf[ks] = __builtin_bit_cast(bf16x8, *(const u16x8*)(qg + qrow * NH + ks * 32 + lg * 8));

  f32x4 o[4];
#pragma unroll
  for (int nt = 0; nt < 4; ++nt) o[nt] = (f32x4){0.f, 0.f, 0.f, 0.f};
  float mrow[4] = {-1e30f, -1e30f, -1e30f, -1e30f};
  float lrow[4] = {0.f, 0.f, 0.f, 0.f};

  for (int kt = 0; kt <= qt; ++kt) {
    // stage K [kv][h] and V^T [h][kv]
#pragma unroll
    for (int i = 0; i < 2; ++i) {
      int flat = tid + 256 * i;            // 512 vec8s each
      int r = flat >> 3, c0 = (flat & 7) * 8;
      *(u16x8*)&ksl[r * 72 + c0] =
          *(const u16x8*)(kg + (b * NT + kt * 64 + r) * NH + c0);
      *(u16x8*)&vsl[r * 72 + c0] =
          *(const u16x8*)(vtg + (b * NH + r) * NT + kt * 64 + c0);
    }
    __syncthreads();

    // S = Q K^T : D[m=q(4lg+r)][n=kv(16nt+lr)]
    f32x4 s[4];
#pragma unroll
    for (int nt = 0; nt < 4; ++nt) {
      s[nt] = (f32x4){0.f, 0.f, 0.f, 0.f};
#pragma unroll
      for (int ks = 0; ks < 2; ++ks) {
        bf16x8 bf = ldsv8(&ksl[(nt * 16 + lr) * 72 + ks * 32 + lg * 8]);
        s[nt] = __builtin_amdgcn_mfma_f32_16x16x32_bf16(qf[ks], bf, s[nt], 0, 0, 0);
      }
    }
    // causal mask on diagonal tile
    if (kt == qt) {
#pragma unroll
      for (int nt = 0; nt < 4; ++nt)
#pragma unroll
        for (int r = 0; r < 4; ++r) {
          int colg = nt * 16 + lr;
          int rowg = w * 16 + lg * 4 + r;   // same 64-block, compare local
          if (colg > rowg) s[nt][r] = -1e30f;
        }
    }
    // online softmax: row reductions across the 16 low lanes
    float tm[4];
#pragma unroll
    for (int r = 0; r < 4; ++r)
      tm[r] = fmaxf(fmaxf(s[0][r], s[1][r]), fmaxf(s[2][r], s[3][r]));
#pragma unroll
    for (int msk = 1; msk < 16; msk <<= 1)
#pragma unroll
      for (int r = 0; r < 4; ++r) tm[r] = fmaxf(tm[r], __shfl_xor(tm[r], msk));
    float al[4];
#pragma unroll
    for (int r = 0; r < 4; ++r) {
      float nm = fmaxf(mrow[r], tm[r]);
      al[r] = exp2f((mrow[r] - nm) * L2E);
      mrow[r] = nm;
    }
    float p[4][4];
#pragma unroll
    for (int nt = 0; nt < 4; ++nt)
#pragma unroll
      for (int r = 0; r < 4; ++r) p[nt][r] = exp2f((s[nt][r] - mrow[r]) * L2E);
    float ts[4];
#pragma unroll
    for (int r = 0; r < 4; ++r) ts[r] = (p[0][r] + p[1][r]) + (p[2][r] + p[3][r]);
#pragma unroll
    for (int msk = 1; msk < 16; msk <<= 1)
#pragma unroll
      for (int r = 0; r < 4; ++r) ts[r] += __shfl_xor(ts[r], msk);
#pragma unroll
    for (int r = 0; r < 4; ++r) lrow[r] = lrow[r] * al[r] + ts[r];
#pragma unroll
    for (int nt = 0; nt < 4; ++nt)
#pragma unroll
      for (int r = 0; r < 4; ++r) o[nt][r] *= al[r];

    // P -> per-wave LDS tile [16 q][64 kv], then PV
#pragma unroll
    for (int nt = 0; nt < 4; ++nt)
#pragma unroll
      for (int r = 0; r < 4; ++r)
        pl[w * 1152 + (lg * 4 + r) * 72 + nt * 16 + lr] = f2bf(p[nt][r]);
#pragma unroll
    for (int nt = 0; nt < 4; ++nt)
#pragma unroll
      for (int ks = 0; ks < 2; ++ks) {
        bf16x8 af = ldsv8(&pl[w * 1152 + lr * 72 + ks * 32 + lg * 8]);
        bf16x8 bf = ldsv8(&vsl[(nt * 16 + lr) * 72 + ks * 32 + lg * 8]);
        o[nt] = __builtin_amdgcn_mfma_f32_16x16x32_bf16(af, bf, o[nt], 0, 0, 0);
      }
    __syncthreads();
  }

  // epilogue: out[b][q][h] fp32
#pragma unroll
  for (int r = 0; r < 4; ++r) {
    float rc = 1.f / lrow[r];
#pragma unroll
    for (int nt = 0; nt < 4; ++nt)
      out[(b * NT + qt * 64 + w * 16 + lg * 4 + r) * NH + nt * 16 + lr] =
          o[nt][r] * rc;
  }
}

extern "C" void kernel_launch(void* const* d_in, const int* in_sizes, int n_in,
                              void* d_out, int out_size, void* d_ws, size_t ws_size,
                              hipStream_t stream) {
  const float* x = (const float*)d_in[0];
  const float* wk = (const float*)d_in[1];
  const float* wq = (const float*)d_in[2];
  const float* wv = (const float*)d_in[3];
  float* out = (float*)d_out;

  u16* qg = (u16*)d_ws;                 // [B*T][H] bf16
  u16* kg = qg + NB * NT * NH;          // [B*T][H] bf16
  u16* vtg = kg + NB * NT * NH;         // [B][H][T] bf16
  u16* wb = vtg + NB * NT * NH;         // [3][H][C] bf16

  wconv<<<768, 256, 0, stream>>>(wk, wq, wv, wb);
  qkv_proj<<<NB * NT / 64, 256, 0, stream>>>(x, wb, qg, kg, vtg);
  flash<<<NB * 32, 256, 0, stream>>>(qg, kg, vtg, out);
}

// Round 2
// 72.029 us; speedup vs baseline: 1.2591x; 1.2591x over previous
//
#include <hip/hip_runtime.h>
#include <hip/hip_bf16.h>

typedef short bf16x8 __attribute__((ext_vector_type(8)));
typedef float f32x4 __attribute__((ext_vector_type(4)));
typedef unsigned short u16;
typedef u16 u16x8 __attribute__((ext_vector_type(8)));
typedef u16 u16x4 __attribute__((ext_vector_type(4)));

constexpr int NB = 8, NT = 2048, NC = 1024, NH = 64;
constexpr float L2E = 1.4426950408889634f;

__device__ __forceinline__ u16 f2bf(float f) {
  __hip_bfloat16 h = __float2bfloat16(f);
  return __builtin_bit_cast(u16, h);
}
__device__ __forceinline__ bf16x8 ldsv8(const u16* p) {
  return __builtin_bit_cast(bf16x8, *(const u16x8*)p);
}

// ---------------- kernel 0: W fp32 [C][H] -> bf16 W^T [3][H][C], q scaled by 0.125
__global__ __launch_bounds__(256) void wconv(const float* __restrict__ wk,
                                             const float* __restrict__ wq,
                                             const float* __restrict__ wv,
                                             u16* __restrict__ wb) {
  int idx = blockIdx.x * 256 + threadIdx.x;   // 3*64*1024 = 196608 exact
  int m = idx >> 16;
  int rem = idx & 65535;
  int n = rem >> 10, kk = rem & 1023;
  const float* src = (m == 0) ? wq : ((m == 1) ? wk : wv);
  float f = src[kk * NH + n];
  if (m == 0) f *= 0.125f;                    // fold 1/sqrt(H) into Wq
  wb[idx] = f2bf(f);
}

// ---------------- kernel 1: fused QKV projection (x read once)
// out: qg,kg = [B*T][H] bf16 ; vtg = [B][H][T] bf16 (transposed for flash PV)
__global__ __launch_bounds__(256) void qkv_proj(const float* __restrict__ x,
                                                const u16* __restrict__ wb,
                                                u16* __restrict__ qg,
                                                u16* __restrict__ kg,
                                                u16* __restrict__ vtg) {
  __shared__ __align__(16) u16 xs[64 * 72];
  __shared__ __align__(16) u16 wt[3 * 64 * 72];
  const int tid = threadIdx.x;
  const int w = tid >> 6, l = tid & 63;
  const int lr = l & 15, lg = l >> 4;
  const int row0 = blockIdx.x * 64;

  f32x4 acc[3][4];
#pragma unroll
  for (int m = 0; m < 3; ++m)
#pragma unroll
    for (int nt = 0; nt < 4; ++nt) acc[m][nt] = (f32x4){0.f, 0.f, 0.f, 0.f};

  for (int kb = 0; kb < 16; ++kb) {
    const int kbase = kb * 64;
#pragma unroll
    for (int i = 0; i < 4; ++i) {
      int flat = tid + 256 * i;            // 1024 float4s
      int r = flat >> 4, c4 = (flat & 15) * 4;
      float4 v = *(const float4*)(x + (row0 + r) * NC + kbase + c4);
      u16x4 pk = {f2bf(v.x), f2bf(v.y), f2bf(v.z), f2bf(v.w)};
      *(u16x4*)&xs[r * 72 + c4] = pk;
    }
#pragma unroll
    for (int i = 0; i < 6; ++i) {
      int flat = tid + 256 * i;            // 1536 vec8s
      int m = flat >> 9, rem = flat & 511;
      int n = rem >> 3, c8 = (rem & 7) * 8;
      u16x8 v = *(const u16x8*)(wb + m * 65536 + n * 1024 + kbase + c8);
      *(u16x8*)&wt[(m * 64 + n) * 72 + c8] = v;
    }
    __syncthreads();
    bf16x8 af[2];
#pragma unroll
    for (int ks = 0; ks < 2; ++ks)
      af[ks] = ldsv8(&xs[(w * 16 + lr) * 72 + ks * 32 + lg * 8]);
#pragma unroll
    for (int m = 0; m < 3; ++m)
#pragma unroll
      for (int nt = 0; nt < 4; ++nt)
#pragma unroll
        for (int ks = 0; ks < 2; ++ks) {
          bf16x8 bf = ldsv8(&wt[(m * 64 + nt * 16 + lr) * 72 + ks * 32 + lg * 8]);
          acc[m][nt] = __builtin_amdgcn_mfma_f32_16x16x32_bf16(af[ks], bf, acc[m][nt], 0, 0, 0);
        }
    __syncthreads();
  }

#pragma unroll
  for (int nt = 0; nt < 4; ++nt)
#pragma unroll
    for (int r = 0; r < 4; ++r) {
      int grow = row0 + w * 16 + lg * 4 + r;
      int col = nt * 16 + lr;
      qg[grow * NH + col] = f2bf(acc[0][nt][r]);
      kg[grow * NH + col] = f2bf(acc[1][nt][r]);
    }
#pragma unroll
  for (int nt = 0; nt < 4; ++nt)
#pragma unroll
    for (int r = 0; r < 4; ++r)
      xs[(w * 16 + lg * 4 + r) * 72 + nt * 16 + lr] = f2bf(acc[2][nt][r]);
  __syncthreads();
  int b = row0 >> 11;
  int t0 = row0 & 2047;
#pragma unroll
  for (int i = 0; i < 2; ++i) {
    int flat = tid + 256 * i;              // 512 vec8s: 64 h-rows x 8
    int h = flat >> 3, tc = (flat & 7) * 8;
    u16x8 v;
#pragma unroll
    for (int j = 0; j < 8; ++j) v[j] = xs[(tc + j) * 72 + h];
    *(u16x8*)(vtg + (b * NH + h) * NT + t0 + tc) = v;
  }
}

// ---------------- kernel 2: causal flash attention, barrier-free inner loop
// 512 blocks x 8 waves. Block handles one (b, j) 32-row q-tile.
// wave w: slice s=w&1 (16 q rows), kv-parity p=w>>2? no: p=w>>1 (kt%4==p).
// K/V frags read directly from global (L2-resident per XCD via b=u&7 swizzle).
__global__ __launch_bounds__(512, 4) void flash(const u16* __restrict__ qg,
                                                const u16* __restrict__ kg,
                                                const u16* __restrict__ vtg,
                                                float* __restrict__ out) {
  __shared__ float Of[2][16][68];
  __shared__ float Ml[2][4][2][16];
  __shared__ __align__(16) u16 pl[8][16 * 72];

  const int tid = threadIdx.x;
  const int w = tid >> 6, l = tid & 63;
  const int lr = l & 15, lg = l >> 4;
  const int s = w & 1, par = w >> 1;

  const int u = blockIdx.x;
  const int pidx = u & 255, hh = u >> 8;
  const int b = pidx & 7;                    // batch == XCD (u%8)
  const int g = pidx >> 3;
  const int j = hh ? 63 - g : g;             // heavy+light share a CU
  const int nkt = (j + 2) >> 1;              // kv tiles of 64 for this q-tile
  const int qrow0 = j * 32 + s * 16;         // within batch

  // Q A-frags (scaled by 0.125 via Wq): A[m=lr][k=h]
  bf16x8 qf[2];
  {
    const u16* qp = qg + (b * NT + qrow0 + lr) * NH;
#pragma unroll
    for (int ks = 0; ks < 2; ++ks)
      qf[ks] = ldsv8(qp + ks * 32 + lg * 8);
  }

  const u16* kb_p = kg + b * NT * NH;
  const u16* vb_p = vtg + b * NH * NT;
  u16* plw = &pl[w][0];

  f32x4 o[4];
#pragma unroll
  for (int nt = 0; nt < 4; ++nt) o[nt] = (f32x4){0.f, 0.f, 0.f, 0.f};
  float mrow[4] = {-1e30f, -1e30f, -1e30f, -1e30f};
  float lrow[4] = {0.f, 0.f, 0.f, 0.f};

  for (int kt = par; kt < nkt; kt += 4) {
    // S = Q K^T : D[m=q(4lg+r)][n=kv(16nt+lr)], K-frags from global
    f32x4 sv[4];
#pragma unroll
    for (int nt = 0; nt < 4; ++nt) {
      sv[nt] = (f32x4){0.f, 0.f, 0.f, 0.f};
#pragma unroll
      for (int ks = 0; ks < 2; ++ks) {
        bf16x8 kf = ldsv8(kb_p + (kt * 64 + nt * 16 + lr) * NH + ks * 32 + lg * 8);
        sv[nt] = __builtin_amdgcn_mfma_f32_16x16x32_bf16(qf[ks], kf, sv[nt], 0, 0, 0);
      }
    }
    if (kt == nkt - 1) {                     // causal mask, global indices
#pragma unroll
      for (int nt = 0; nt < 4; ++nt)
#pragma unroll
        for (int r = 0; r < 4; ++r)
          if (kt * 64 + nt * 16 + lr > qrow0 + lg * 4 + r) sv[nt][r] = -1e30f;
    }
    // online softmax (row reduce over the 16 lr lanes)
    float tm[4];
#pragma unroll
    for (int r = 0; r < 4; ++r)
      tm[r] = fmaxf(fmaxf(sv[0][r], sv[1][r]), fmaxf(sv[2][r], sv[3][r]));
#pragma unroll
    for (int msk = 1; msk < 16; msk <<= 1)
#pragma unroll
      for (int r = 0; r < 4; ++r) tm[r] = fmaxf(tm[r], __shfl_xor(tm[r], msk));
    float al[4];
#pragma unroll
    for (int r = 0; r < 4; ++r) {
      float nm = fmaxf(mrow[r], tm[r]);
      al[r] = exp2f((mrow[r] - nm) * L2E);
      mrow[r] = nm;
    }
#pragma unroll
    for (int nt = 0; nt < 4; ++nt)
#pragma unroll
      for (int r = 0; r < 4; ++r)
        sv[nt][r] = exp2f((sv[nt][r] - mrow[r]) * L2E);  // reuse sv as P
    float ts[4];
#pragma unroll
    for (int r = 0; r < 4; ++r) ts[r] = (sv[0][r] + sv[1][r]) + (sv[2][r] + sv[3][r]);
#pragma unroll
    for (int msk = 1; msk < 16; msk <<= 1)
#pragma unroll
      for (int r = 0; r < 4; ++r) ts[r] += __shfl_xor(ts[r], msk);
#pragma unroll
    for (int r = 0; r < 4; ++r) lrow[r] = lrow[r] * al[r] + ts[r];
#pragma unroll
    for (int nt = 0; nt < 4; ++nt)
#pragma unroll
      for (int r = 0; r < 4; ++r) o[nt][r] *= al[r];

    // P -> per-wave LDS tile [16 q][64 kv] (wave-private, no barrier), then PV
#pragma unroll
    for (int nt = 0; nt < 4; ++nt)
#pragma unroll
      for (int r = 0; r < 4; ++r)
        plw[(lg * 4 + r) * 72 + nt * 16 + lr] = f2bf(sv[nt][r]);
#pragma unroll
    for (int nt = 0; nt < 4; ++nt)
#pragma unroll
      for (int ks = 0; ks < 2; ++ks) {
        bf16x8 af = ldsv8(plw + lr * 72 + ks * 32 + lg * 8);
        bf16x8 vf = ldsv8(vb_p + (nt * 16 + lr) * NT + kt * 64 + ks * 32 + lg * 8);
        o[nt] = __builtin_amdgcn_mfma_f32_16x16x32_bf16(af, vf, o[nt], 0, 0, 0);
      }
  }

  // -------- merge the 4 kv-parity partials per slice --------
  if (lr == 0) {
#pragma unroll
    for (int r = 0; r < 4; ++r) {
      Ml[s][par][0][lg * 4 + r] = mrow[r];
      Ml[s][par][1][lg * 4 + r] = lrow[r];
    }
  }
  __syncthreads();
  float fac[4];
#pragma unroll
  for (int r = 0; r < 4; ++r) {
    int row = lg * 4 + r;
    float mm = Ml[s][0][0][row];
#pragma unroll
    for (int p = 1; p < 4; ++p) mm = fmaxf(mm, Ml[s][p][0][row]);
    float ll = 0.f;
#pragma unroll
    for (int p = 0; p < 4; ++p)
      ll += exp2f((Ml[s][p][0][row] - mm) * L2E) * Ml[s][p][1][row];
    fac[r] = exp2f((mrow[r] - mm) * L2E) / ll;
  }
#pragma unroll
  for (int nt = 0; nt < 4; ++nt)
#pragma unroll
    for (int r = 0; r < 4; ++r) o[nt][r] *= fac[r];

#pragma unroll
  for (int p = 0; p < 4; ++p) {
    __syncthreads();
    if (par == p) {
#pragma unroll
      for (int nt = 0; nt < 4; ++nt)
#pragma unroll
        for (int r = 0; r < 4; ++r) {
          int row = lg * 4 + r, col = nt * 16 + lr;
          if (p == 0) Of[s][row][col] = o[nt][r];
          else        Of[s][row][col] += o[nt][r];
        }
    }
  }
  __syncthreads();
  if (par == 0) {
#pragma unroll
    for (int c = 0; c < 4; ++c) {
      f32x4 vv = *(const f32x4*)&Of[s][lr][lg * 16 + c * 4];
      *(f32x4*)&out[(b * NT + qrow0 + lr) * NH + lg * 16 + c * 4] = vv;
    }
  }
}

extern "C" void kernel_launch(void* const* d_in, const int* in_sizes, int n_in,
                              void* d_out, int out_size, void* d_ws, size_t ws_size,
                              hipStream_t stream) {
  const float* x = (const float*)d_in[0];
  const float* wk = (const float*)d_in[1];
  const float* wq = (const float*)d_in[2];
  const float* wv = (const float*)d_in[3];
  float* out = (float*)d_out;

  u16* qg = (u16*)d_ws;                 // [B*T][H] bf16
  u16* kg = qg + NB * NT * NH;          // [B*T][H] bf16
  u16* vtg = kg + NB * NT * NH;         // [B][H][T] bf16
  u16* wb = vtg + NB * NT * NH;         // [3][H][C] bf16

  wconv<<<768, 256, 0, stream>>>(wk, wq, wv, wb);
  qkv_proj<<<NB * NT / 64, 256, 0, stream>>>(x, wb, qg, kg, vtg);
  flash<<<NB * 64, 512, 0, stream>>>(qg, kg, vtg, out);
}